// Round 4
// baseline (500.968 us; speedup 1.0000x reference)
//
#include <hip/hip_runtime.h>
#include <hip/hip_bf16.h>
#include <stdint.h>

#define NTOK 8192
#define DIN  256
#define DOUT 256
#define NEXP 16
#define HID  512
#define NKA  (NTOK*2)   // total assignments
#define NBLK (NTOK/256) // routing blocks

typedef __bf16 bf16x8 __attribute__((ext_vector_type(8)));
typedef __bf16 bf16x4 __attribute__((ext_vector_type(4)));
typedef float  f32x4  __attribute__((ext_vector_type(4)));

// ---------------- convert x (fp32 -> bf16) ----------------
__global__ void cvt_x_kernel(const float* __restrict__ x, __bf16* __restrict__ xb) {
  int i = blockIdx.x * blockDim.x + threadIdx.x;
  float4 v = ((const float4*)x)[i];
  bf16x4 o = { (__bf16)v.x, (__bf16)v.y, (__bf16)v.z, (__bf16)v.w };
  ((bf16x4*)xb)[i] = o;
}

// ------- transpose-convert weights: src[k][e][n] fp32 -> dst[e][n][k] bf16 -------
__global__ void transpose_cvt_kernel(const float* __restrict__ src, __bf16* __restrict__ dst,
                                     int K, int N) {
  __shared__ float t[32][33];
  int e  = blockIdx.z;
  int k0 = blockIdx.x * 32, n0 = blockIdx.y * 32;
  int tx = threadIdx.x, ty = threadIdx.y;          // 32 x 8
  #pragma unroll
  for (int j = 0; j < 4; j++) {
    int kl = ty + j * 8;
    t[kl][tx] = src[(size_t)(k0 + kl) * (NEXP * N) + (size_t)e * N + n0 + tx];
  }
  __syncthreads();
  #pragma unroll
  for (int j = 0; j < 4; j++) {
    int nl = ty + j * 8;
    dst[(size_t)e * N * K + (size_t)(n0 + nl) * K + k0 + tx] = (__bf16)t[tx][nl];
  }
}

// ------- gate hidden GEMM, fp32 vector: hg = relu(x @ gate_w + gate_b) -------
// 128x128 block tile, 256 threads, 8x8 per thread, BK=16. A staged k-major (AlT)
// so all compute-phase LDS reads are b128. 1 B/FMA LDS traffic.
__global__ __launch_bounds__(256) void gate_gemm_kernel(const float* __restrict__ A,
                                                        const float* __restrict__ B,
                                                        const float* __restrict__ bias,
                                                        float* __restrict__ out) {
  const int K = DIN, N = HID;
  __shared__ float AlT[16][132];   // [k][m]
  __shared__ float Bl[16][132];    // [k][n]
  int m0 = blockIdx.x * 128, n0 = blockIdx.y * 128;
  int tid = threadIdx.x;
  int tx = tid & 15, ty = tid >> 4;
  float acc[8][8] = {};

  // staging indices: A: thread -> row tid>>1, 8 floats at k-off (tid&1)*8
  int am = tid >> 1, ak = (tid & 1) * 8;
  // B: thread -> k-row tid>>4, 8 floats at col (tid&15)*8
  int bk = tid >> 4, bn = (tid & 15) * 8;

  for (int kb = 0; kb < K; kb += 16) {
    float4 va0 = *(const float4*)&A[(size_t)(m0 + am) * K + kb + ak];
    float4 va1 = *(const float4*)&A[(size_t)(m0 + am) * K + kb + ak + 4];
    float4 vb0 = *(const float4*)&B[(size_t)(kb + bk) * N + n0 + bn];
    float4 vb1 = *(const float4*)&B[(size_t)(kb + bk) * N + n0 + bn + 4];
    __syncthreads();
    AlT[ak + 0][am] = va0.x; AlT[ak + 1][am] = va0.y;
    AlT[ak + 2][am] = va0.z; AlT[ak + 3][am] = va0.w;
    AlT[ak + 4][am] = va1.x; AlT[ak + 5][am] = va1.y;
    AlT[ak + 6][am] = va1.z; AlT[ak + 7][am] = va1.w;
    *(float4*)&Bl[bk][bn] = vb0;
    *(float4*)&Bl[bk][bn + 4] = vb1;
    __syncthreads();
    #pragma unroll
    for (int k = 0; k < 16; k++) {
      float4 a0 = *(const float4*)&AlT[k][ty * 8];
      float4 a1 = *(const float4*)&AlT[k][ty * 8 + 4];
      float4 b0 = *(const float4*)&Bl[k][tx * 8];
      float4 b1 = *(const float4*)&Bl[k][tx * 8 + 4];
      float av[8] = {a0.x,a0.y,a0.z,a0.w,a1.x,a1.y,a1.z,a1.w};
      float bv[8] = {b0.x,b0.y,b0.z,b0.w,b1.x,b1.y,b1.z,b1.w};
      #pragma unroll
      for (int i = 0; i < 8; i++)
        #pragma unroll
        for (int j = 0; j < 8; j++)
          acc[i][j] = fmaf(av[i], bv[j], acc[i][j]);
    }
  }
  float bv0[8];
  #pragma unroll
  for (int j = 0; j < 8; j++) bv0[j] = bias[n0 + tx * 8 + j];
  #pragma unroll
  for (int i = 0; i < 8; i++) {
    int m = m0 + ty * 8 + i;
    float4 o0, o1;
    o0.x = fmaxf(acc[i][0] + bv0[0], 0.f); o0.y = fmaxf(acc[i][1] + bv0[1], 0.f);
    o0.z = fmaxf(acc[i][2] + bv0[2], 0.f); o0.w = fmaxf(acc[i][3] + bv0[3], 0.f);
    o1.x = fmaxf(acc[i][4] + bv0[4], 0.f); o1.y = fmaxf(acc[i][5] + bv0[5], 0.f);
    o1.z = fmaxf(acc[i][6] + bv0[6], 0.f); o1.w = fmaxf(acc[i][7] + bv0[7], 0.f);
    *(float4*)&out[(size_t)m * N + n0 + tx * 8] = o0;
    *(float4*)&out[(size_t)m * N + n0 + tx * 8 + 4] = o1;
  }
}

// ---------------- logits = hg @ gate_out_w + gate_out_b  (fp32) ----------------
__global__ __launch_bounds__(128) void logits_kernel(const float* __restrict__ hg,
                                                     const float* __restrict__ gw,
                                                     const float* __restrict__ gb,
                                                     float* __restrict__ logits) {
  __shared__ float hl[8][HID];
  __shared__ float wl[HID][16];
  int t0 = blockIdx.x * 8;
  int tid = threadIdx.x;
  for (int c = tid; c < 8 * (HID / 4); c += 128) {
    int row = c >> 7, col = (c & 127) * 4;
    *(float4*)&hl[row][col] = *(const float4*)&hg[(size_t)(t0 + row) * HID + col];
  }
  for (int c = tid; c < HID * 4; c += 128) {
    int k = c >> 2, e4 = (c & 3) * 4;
    *(float4*)&wl[k][e4] = *(const float4*)&gw[(size_t)k * 16 + e4];
  }
  __syncthreads();
  int tok = tid >> 4, e = tid & 15;
  float s = gb[e];
  #pragma unroll 8
  for (int k = 0; k < HID; k++) s = fmaf(hl[tok][k], wl[k][e], s);
  logits[(size_t)(t0 + tok) * 16 + e] = s;
}

// ---------------- top-2 + softmax + block-local histogram/ranks ----------------
__global__ __launch_bounds__(256) void top2_route_kernel(const float* __restrict__ logits,
                                                         int2* __restrict__ e01,
                                                         float2* __restrict__ g01,
                                                         int* __restrict__ lrank,
                                                         int* __restrict__ blockhist) {
  __shared__ int hist[NEXP];
  int tid = threadIdx.x;
  if (tid < NEXP) hist[tid] = 0;
  __syncthreads();
  int t = blockIdx.x * 256 + tid;
  float lv[16];
  const float4* lp = (const float4*)(logits + (size_t)t * 16);
  #pragma unroll
  for (int j = 0; j < 4; j++) { float4 v = lp[j]; lv[4*j]=v.x; lv[4*j+1]=v.y; lv[4*j+2]=v.z; lv[4*j+3]=v.w; }
  float v0 = -3.402823466e38f, v1 = -3.402823466e38f;
  int i0 = 0, i1 = 0;
  #pragma unroll
  for (int e = 0; e < 16; e++) {
    float v = lv[e];
    if (v > v0) { v1 = v0; i1 = i0; v0 = v; i0 = e; }
    else if (v > v1) { v1 = v; i1 = e; }
  }
  float ew = expf(v1 - v0);
  float inv = 1.f / (1.f + ew);
  e01[t] = make_int2(i0, i1);
  g01[t] = make_float2(inv, ew * inv);
  int r0 = atomicAdd(&hist[i0], 1);
  int r1 = atomicAdd(&hist[i1], 1);
  lrank[2 * t]     = r0;
  lrank[2 * t + 1] = r1;
  __syncthreads();
  if (tid < NEXP) blockhist[blockIdx.x * NEXP + tid] = hist[tid];
}

// ---------------- scan: offsets per expert + per-(block,expert) base ----------------
__global__ void scan2_kernel(const int* __restrict__ blockhist, int* __restrict__ offsets,
                             int* __restrict__ base) {
  __shared__ int tot[NEXP];
  __shared__ int soff[NEXP + 1];
  int e = threadIdx.x;
  if (e < NEXP) {
    int s = 0;
    for (int b = 0; b < NBLK; b++) s += blockhist[b * NEXP + e];
    tot[e] = s;
  }
  __syncthreads();
  if (e == 0) {
    int s = 0;
    for (int i = 0; i < NEXP; i++) { soff[i] = s; s += tot[i]; }
    soff[NEXP] = s;
  }
  __syncthreads();
  if (e < NEXP + 1) offsets[e] = soff[e];
  if (e < NEXP) {
    int s = soff[e];
    for (int b = 0; b < NBLK; b++) { base[b * NEXP + e] = s; s += blockhist[b * NEXP + e]; }
  }
}

// ---------------- fill: atomic-free scatter using (base, lrank) ----------------
__global__ __launch_bounds__(256) void fill2_kernel(const int2* __restrict__ e01,
                                                    const int* __restrict__ lrank,
                                                    const int* __restrict__ base,
                                                    int* __restrict__ tok_sorted,
                                                    int* __restrict__ route_pos) {
  int b = blockIdx.x;
  int t = b * 256 + threadIdx.x;
  int2 e = e01[t];
  int p0 = base[b * NEXP + e.x] + lrank[2 * t];
  int p1 = base[b * NEXP + e.y] + lrank[2 * t + 1];
  tok_sorted[p0] = t; route_pos[2 * t]     = p0;
  tok_sorted[p1] = t; route_pos[2 * t + 1] = p1;
}

// ------- grouped expert GEMM: LDS-FREE, direct-from-L2 MFMA operand loads -------
// Block = 256 thr = 4 waves in 2x2 over a 128x128 tile; wave tile 64x64 = 4x4
// frags of 16x16x32. No barriers, no LDS -> no compiler waitcnt drains; K-loop
// register-double-buffered. Fragment loads are 16-row x 64 B segment-coalesced.
template<int K, int N, bool OUT_F32, bool RELU>
__global__ __launch_bounds__(256) void moe_gemm_kernel(const __bf16* __restrict__ A,
                                                       const __bf16* __restrict__ Bt,
                                                       const float* __restrict__ bias,
                                                       void* __restrict__ out,
                                                       const int* __restrict__ seg_off,
                                                       const int* __restrict__ gather) {
  int e = blockIdx.z;
  int off = seg_off[e];
  int Te  = seg_off[e + 1] - off;
  int mt = blockIdx.x;
  if (mt * 128 >= Te) return;
  int nt = blockIdx.y;

  int tid = threadIdx.x;
  int lane = tid & 63, w = tid >> 6;
  int wm = (w >> 1) * 64, wn = (w & 1) * 64;
  int l16 = lane & 15, quad = lane >> 4;

  const __bf16* Ap[4];
  #pragma unroll
  for (int i = 0; i < 4; i++) {
    int m = mt * 128 + wm + i * 16 + l16;
    if (m >= Te) m = Te - 1;
    int ri = gather ? gather[off + m] : (off + m);
    Ap[i] = A + (size_t)ri * K + quad * 8;
  }
  const __bf16* Bp[4];
  {
    const __bf16* Be = Bt + (size_t)e * N * K + quad * 8;
    #pragma unroll
    for (int i = 0; i < 4; i++)
      Bp[i] = Be + (size_t)(nt * 128 + wn + i * 16 + l16) * K;
  }

  f32x4 acc[4][4];
  #pragma unroll
  for (int i = 0; i < 4; i++)
    #pragma unroll
    for (int j = 0; j < 4; j++) acc[i][j] = {0.f, 0.f, 0.f, 0.f};

  bf16x8 a[2][4], b[2][4];
  #pragma unroll
  for (int i = 0; i < 4; i++) {
    a[0][i] = *(const bf16x8*)(Ap[i]);
    b[0][i] = *(const bf16x8*)(Bp[i]);
  }
  constexpr int NIT = K / 32;
  #pragma unroll
  for (int it = 0; it < NIT; it++) {
    int cur = it & 1, nxt = cur ^ 1;
    if (it + 1 < NIT) {
      #pragma unroll
      for (int i = 0; i < 4; i++) {
        a[nxt][i] = *(const bf16x8*)(Ap[i] + (it + 1) * 32);
        b[nxt][i] = *(const bf16x8*)(Bp[i] + (it + 1) * 32);
      }
    }
    #pragma unroll
    for (int mi = 0; mi < 4; mi++)
      #pragma unroll
      for (int ni = 0; ni < 4; ni++)
        acc[mi][ni] = __builtin_amdgcn_mfma_f32_16x16x32_bf16(a[cur][mi], b[cur][ni], acc[mi][ni], 0, 0, 0);
  }

  const float* be = bias + (size_t)e * N;
  #pragma unroll
  for (int ni = 0; ni < 4; ni++) {
    int col = nt * 128 + wn + ni * 16 + l16;
    float bv = be[col];
    #pragma unroll
    for (int mi = 0; mi < 4; mi++) {
      #pragma unroll
      for (int r = 0; r < 4; r++) {
        int row_in = mt * 128 + wm + mi * 16 + quad * 4 + r;
        if (row_in < Te) {
          float v = acc[mi][ni][r] + bv;
          if (RELU) v = fmaxf(v, 0.f);
          size_t orow = (size_t)(off + row_in);
          if (OUT_F32) ((float*)out)[orow * N + col] = v;
          else ((__bf16*)out)[orow * N + col] = (__bf16)v;
        }
      }
    }
  }
}

// ---------------- final combine: out[t] = g0*Y[p0] + g1*Y[p1] ----------------
__global__ void combine_kernel(const float* __restrict__ Y, const int* __restrict__ route_pos,
                               const float2* __restrict__ g01, float* __restrict__ out) {
  int gid = blockIdx.x * blockDim.x + threadIdx.x;
  int t = gid >> 6, c = (gid & 63) << 2;
  if (t >= NTOK) return;
  int p0 = route_pos[2 * t], p1 = route_pos[2 * t + 1];
  float2 g = g01[t];
  float4 y0 = *(const float4*)&Y[(size_t)p0 * DOUT + c];
  float4 y1 = *(const float4*)&Y[(size_t)p1 * DOUT + c];
  float4 o;
  o.x = g.x * y0.x + g.y * y1.x;
  o.y = g.x * y0.y + g.y * y1.y;
  o.z = g.x * y0.z + g.y * y1.z;
  o.w = g.x * y0.w + g.y * y1.w;
  *(float4*)&out[(size_t)t * DOUT + c] = o;
}

// ---------------- launcher ----------------
extern "C" void kernel_launch(void* const* d_in, const int* in_sizes, int n_in,
                              void* d_out, int out_size, void* d_ws, size_t ws_size,
                              hipStream_t stream) {
  const float* x          = (const float*)d_in[0];
  const float* gate_w     = (const float*)d_in[1];
  const float* gate_b     = (const float*)d_in[2];
  const float* gate_out_w = (const float*)d_in[3];
  const float* gate_out_b = (const float*)d_in[4];
  const float* w1         = (const float*)d_in[5];
  const float* b1         = (const float*)d_in[6];
  const float* w2         = (const float*)d_in[7];
  const float* b2         = (const float*)d_in[8];
  const float* w3         = (const float*)d_in[9];
  const float* b3         = (const float*)d_in[10];
  float* out = (float*)d_out;

  char* ws = (char*)d_ws;
  size_t o = 0;
  auto alloc = [&](size_t bytes) -> void* {
    o = (o + 255) & ~(size_t)255;
    void* p = ws + o;
    o += bytes;
    return p;
  };

  __bf16* xb   = (__bf16*)alloc((size_t)NTOK * DIN * 2);
  __bf16* w1t  = (__bf16*)alloc((size_t)NEXP * HID * DIN * 2);
  __bf16* w2t  = (__bf16*)alloc((size_t)NEXP * HID * HID * 2);
  __bf16* w3t  = (__bf16*)alloc((size_t)NEXP * DOUT * HID * 2);
  size_t r1 = (size_t)NTOK * HID * 4;
  size_t r2 = (size_t)(NKA + 128) * HID * 2;
  void* region1 = alloc(r1 > r2 ? r1 : r2);   // hg (fp32) aliases H1 (bf16); hg dead first
  float*  hg = (float*)region1;
  __bf16* H1 = (__bf16*)region1;
  float* logits    = (float*)alloc((size_t)NTOK * 16 * 4);
  int2*  e01       = (int2*)alloc((size_t)NTOK * 8);
  float2* g01      = (float2*)alloc((size_t)NTOK * 8);
  int*   offsets   = (int*)alloc((NEXP + 1) * 4);
  int*   blockhist = (int*)alloc((size_t)NBLK * NEXP * 4);
  int*   base      = (int*)alloc((size_t)NBLK * NEXP * 4);
  int*   lrank     = (int*)alloc((size_t)NTOK * 2 * 4);
  int*   tok_sorted= (int*)alloc((size_t)(NKA + 128) * 4);
  int*   route_pos = (int*)alloc((size_t)NTOK * 2 * 4);
  __bf16* H2       = (__bf16*)alloc((size_t)(NKA + 128) * HID * 2);
  float*  Y        = (float*)alloc((size_t)(NKA + 128) * DOUT * 4);
  (void)ws_size; (void)n_in; (void)in_sizes; (void)out_size;

  cvt_x_kernel<<<(NTOK * DIN / 4) / 256, 256, 0, stream>>>(x, xb);

  dim3 tb(32, 8);
  transpose_cvt_kernel<<<dim3(DIN / 32, HID / 32, NEXP), tb, 0, stream>>>(w1, w1t, DIN, HID);
  transpose_cvt_kernel<<<dim3(HID / 32, HID / 32, NEXP), tb, 0, stream>>>(w2, w2t, HID, HID);
  transpose_cvt_kernel<<<dim3(HID / 32, DOUT / 32, NEXP), tb, 0, stream>>>(w3, w3t, HID, DOUT);

  gate_gemm_kernel<<<dim3(NTOK / 128, HID / 128), 256, 0, stream>>>(x, gate_w, gate_b, hg);
  logits_kernel<<<NTOK / 8, 128, 0, stream>>>(hg, gate_out_w, gate_out_b, logits);
  top2_route_kernel<<<NBLK, 256, 0, stream>>>(logits, e01, g01, lrank, blockhist);
  scan2_kernel<<<1, 64, 0, stream>>>(blockhist, offsets, base);
  fill2_kernel<<<NBLK, 256, 0, stream>>>(e01, lrank, base, tok_sorted, route_pos);

  moe_gemm_kernel<DIN, HID, false, true><<<dim3(64, HID / 128, NEXP), 256, 0, stream>>>(
      xb, w1t, b1, H1, offsets, tok_sorted);
  moe_gemm_kernel<HID, HID, false, true><<<dim3(64, HID / 128, NEXP), 256, 0, stream>>>(
      H1, w2t, b2, H2, offsets, nullptr);
  moe_gemm_kernel<HID, DOUT, true, false><<<dim3(64, DOUT / 128, NEXP), 256, 0, stream>>>(
      H2, w3t, b3, Y, offsets, nullptr);

  combine_kernel<<<(NTOK * 64) / 256, 256, 0, stream>>>(Y, route_pos, g01, out);
}

// Round 5
// 247.233 us; speedup vs baseline: 2.0263x; 2.0263x over previous
//
#include <hip/hip_runtime.h>
#include <hip/hip_bf16.h>
#include <stdint.h>

#define NTOK 8192
#define DIN  256
#define DOUT 256
#define NEXP 16
#define HID  512
#define NKA  (NTOK*2)   // total assignments
#define NBLK (NTOK/256) // routing blocks
#define MAXTILE 272     // sum ceil(Te/64) <= 16384/64 + 16

typedef __bf16 bf16x8 __attribute__((ext_vector_type(8)));
typedef __bf16 bf16x4 __attribute__((ext_vector_type(4)));
typedef float  f32x4  __attribute__((ext_vector_type(4)));

// async 16B global -> LDS (DMA; wave-uniform LDS base + lane*16)
__device__ __forceinline__ void async_cp16(const __bf16* g, __bf16* l) {
  __builtin_amdgcn_global_load_lds(
      (const __attribute__((address_space(1))) unsigned int*)g,
      (__attribute__((address_space(3))) unsigned int*)l, 16, 0, 0);
}

// ---------------- convert x (fp32 -> bf16) ----------------
__global__ void cvt_x_kernel(const float* __restrict__ x, __bf16* __restrict__ xb) {
  int i = blockIdx.x * blockDim.x + threadIdx.x;
  float4 v = ((const float4*)x)[i];
  bf16x4 o = { (__bf16)v.x, (__bf16)v.y, (__bf16)v.z, (__bf16)v.w };
  ((bf16x4*)xb)[i] = o;
}

// ------- transpose-convert weights: src[k][e][n] fp32 -> dst[e][n][k] bf16 -------
__global__ void transpose_cvt_kernel(const float* __restrict__ src, __bf16* __restrict__ dst,
                                     int K, int N) {
  __shared__ float t[32][33];
  int e  = blockIdx.z;
  int k0 = blockIdx.x * 32, n0 = blockIdx.y * 32;
  int tx = threadIdx.x, ty = threadIdx.y;          // 32 x 8
  #pragma unroll
  for (int j = 0; j < 4; j++) {
    int kl = ty + j * 8;
    t[kl][tx] = src[(size_t)(k0 + kl) * (NEXP * N) + (size_t)e * N + n0 + tx];
  }
  __syncthreads();
  #pragma unroll
  for (int j = 0; j < 4; j++) {
    int nl = ty + j * 8;
    dst[(size_t)e * N * K + (size_t)(n0 + nl) * K + k0 + tx] = (__bf16)t[tx][nl];
  }
}

// ------- gate hidden GEMM, fp32 vector: hg = relu(x @ gate_w + gate_b) -------
// 128x128 block tile, 256 threads, 8x8 per thread, BK=16, A staged k-major.
__global__ __launch_bounds__(256) void gate_gemm_kernel(const float* __restrict__ A,
                                                        const float* __restrict__ B,
                                                        const float* __restrict__ bias,
                                                        float* __restrict__ out) {
  const int K = DIN, N = HID;
  __shared__ float AlT[16][132];   // [k][m]
  __shared__ float Bl[16][132];    // [k][n]
  int m0 = blockIdx.x * 128, n0 = blockIdx.y * 128;
  int tid = threadIdx.x;
  int tx = tid & 15, ty = tid >> 4;
  float acc[8][8] = {};

  int am = tid >> 1, ak = (tid & 1) * 8;
  int bk = tid >> 4, bn = (tid & 15) * 8;

  for (int kb = 0; kb < K; kb += 16) {
    float4 va0 = *(const float4*)&A[(size_t)(m0 + am) * K + kb + ak];
    float4 va1 = *(const float4*)&A[(size_t)(m0 + am) * K + kb + ak + 4];
    float4 vb0 = *(const float4*)&B[(size_t)(kb + bk) * N + n0 + bn];
    float4 vb1 = *(const float4*)&B[(size_t)(kb + bk) * N + n0 + bn + 4];
    __syncthreads();
    AlT[ak + 0][am] = va0.x; AlT[ak + 1][am] = va0.y;
    AlT[ak + 2][am] = va0.z; AlT[ak + 3][am] = va0.w;
    AlT[ak + 4][am] = va1.x; AlT[ak + 5][am] = va1.y;
    AlT[ak + 6][am] = va1.z; AlT[ak + 7][am] = va1.w;
    *(float4*)&Bl[bk][bn] = vb0;
    *(float4*)&Bl[bk][bn + 4] = vb1;
    __syncthreads();
    #pragma unroll
    for (int k = 0; k < 16; k++) {
      float4 a0 = *(const float4*)&AlT[k][ty * 8];
      float4 a1 = *(const float4*)&AlT[k][ty * 8 + 4];
      float4 b0 = *(const float4*)&Bl[k][tx * 8];
      float4 b1 = *(const float4*)&Bl[k][tx * 8 + 4];
      float av[8] = {a0.x,a0.y,a0.z,a0.w,a1.x,a1.y,a1.z,a1.w};
      float bv[8] = {b0.x,b0.y,b0.z,b0.w,b1.x,b1.y,b1.z,b1.w};
      #pragma unroll
      for (int i = 0; i < 8; i++)
        #pragma unroll
        for (int j = 0; j < 8; j++)
          acc[i][j] = fmaf(av[i], bv[j], acc[i][j]);
    }
  }
  float bv0[8];
  #pragma unroll
  for (int j = 0; j < 8; j++) bv0[j] = bias[n0 + tx * 8 + j];
  #pragma unroll
  for (int i = 0; i < 8; i++) {
    int m = m0 + ty * 8 + i;
    float4 o0, o1;
    o0.x = fmaxf(acc[i][0] + bv0[0], 0.f); o0.y = fmaxf(acc[i][1] + bv0[1], 0.f);
    o0.z = fmaxf(acc[i][2] + bv0[2], 0.f); o0.w = fmaxf(acc[i][3] + bv0[3], 0.f);
    o1.x = fmaxf(acc[i][4] + bv0[4], 0.f); o1.y = fmaxf(acc[i][5] + bv0[5], 0.f);
    o1.z = fmaxf(acc[i][6] + bv0[6], 0.f); o1.w = fmaxf(acc[i][7] + bv0[7], 0.f);
    *(float4*)&out[(size_t)m * N + n0 + tx * 8] = o0;
    *(float4*)&out[(size_t)m * N + n0 + tx * 8 + 4] = o1;
  }
}

// ---------------- logits = hg @ gate_out_w + gate_out_b  (fp32) ----------------
__global__ __launch_bounds__(128) void logits_kernel(const float* __restrict__ hg,
                                                     const float* __restrict__ gw,
                                                     const float* __restrict__ gb,
                                                     float* __restrict__ logits) {
  __shared__ float hl[8][HID];
  __shared__ float wl[HID][16];
  int t0 = blockIdx.x * 8;
  int tid = threadIdx.x;
  for (int c = tid; c < 8 * (HID / 4); c += 128) {
    int row = c >> 7, col = (c & 127) * 4;
    *(float4*)&hl[row][col] = *(const float4*)&hg[(size_t)(t0 + row) * HID + col];
  }
  for (int c = tid; c < HID * 4; c += 128) {
    int k = c >> 2, e4 = (c & 3) * 4;
    *(float4*)&wl[k][e4] = *(const float4*)&gw[(size_t)k * 16 + e4];
  }
  __syncthreads();
  int tok = tid >> 4, e = tid & 15;
  float s = gb[e];
  #pragma unroll 8
  for (int k = 0; k < HID; k++) s = fmaf(hl[tok][k], wl[k][e], s);
  logits[(size_t)(t0 + tok) * 16 + e] = s;
}

// ---------------- top-2 + softmax + block-local histogram/ranks ----------------
__global__ __launch_bounds__(256) void top2_route_kernel(const float* __restrict__ logits,
                                                         int2* __restrict__ e01,
                                                         float2* __restrict__ g01,
                                                         int* __restrict__ lrank,
                                                         int* __restrict__ blockhist) {
  __shared__ int hist[NEXP];
  int tid = threadIdx.x;
  if (tid < NEXP) hist[tid] = 0;
  __syncthreads();
  int t = blockIdx.x * 256 + tid;
  float lv[16];
  const float4* lp = (const float4*)(logits + (size_t)t * 16);
  #pragma unroll
  for (int j = 0; j < 4; j++) { float4 v = lp[j]; lv[4*j]=v.x; lv[4*j+1]=v.y; lv[4*j+2]=v.z; lv[4*j+3]=v.w; }
  float v0 = -3.402823466e38f, v1 = -3.402823466e38f;
  int i0 = 0, i1 = 0;
  #pragma unroll
  for (int e = 0; e < 16; e++) {
    float v = lv[e];
    if (v > v0) { v1 = v0; i1 = i0; v0 = v; i0 = e; }
    else if (v > v1) { v1 = v; i1 = e; }
  }
  float ew = expf(v1 - v0);
  float inv = 1.f / (1.f + ew);
  e01[t] = make_int2(i0, i1);
  g01[t] = make_float2(inv, ew * inv);
  int r0 = atomicAdd(&hist[i0], 1);
  int r1 = atomicAdd(&hist[i1], 1);
  lrank[2 * t]     = r0;
  lrank[2 * t + 1] = r1;
  __syncthreads();
  if (tid < NEXP) blockhist[blockIdx.x * NEXP + tid] = hist[tid];
}

// ------- scan: expert offsets, per-(block,expert) base, and the flat TILE LIST -------
__global__ void scan2_kernel(const int* __restrict__ blockhist, int* __restrict__ offsets,
                             int* __restrict__ base, int* __restrict__ tile_e,
                             int* __restrict__ tile_mt, int* __restrict__ ntiles) {
  __shared__ int tot[NEXP];
  __shared__ int soff[NEXP + 1];
  __shared__ int tbase[NEXP];
  int e = threadIdx.x;
  if (e < NEXP) {
    int s = 0;
    for (int b = 0; b < NBLK; b++) s += blockhist[b * NEXP + e];
    tot[e] = s;
  }
  __syncthreads();
  if (e == 0) {
    int s = 0, tb = 0;
    for (int i = 0; i < NEXP; i++) {
      soff[i] = s; s += tot[i];
      tbase[i] = tb; tb += (tot[i] + 63) >> 6;
    }
    soff[NEXP] = s;
    *ntiles = tb;
  }
  __syncthreads();
  if (e < NEXP + 1) offsets[e] = soff[e];
  if (e < NEXP) {
    int s = soff[e];
    for (int b = 0; b < NBLK; b++) { base[b * NEXP + e] = s; s += blockhist[b * NEXP + e]; }
    int nt = (tot[e] + 63) >> 6, tb = tbase[e];
    for (int m = 0; m < nt; m++) { tile_e[tb + m] = e; tile_mt[tb + m] = m; }
  }
}

// ---------------- fill: atomic-free scatter using (base, lrank) ----------------
__global__ __launch_bounds__(256) void fill2_kernel(const int2* __restrict__ e01,
                                                    const int* __restrict__ lrank,
                                                    const int* __restrict__ base,
                                                    int* __restrict__ tok_sorted,
                                                    int* __restrict__ route_pos) {
  int b = blockIdx.x;
  int t = b * 256 + threadIdx.x;
  int2 e = e01[t];
  int p0 = base[b * NEXP + e.x] + lrank[2 * t];
  int p1 = base[b * NEXP + e.y] + lrank[2 * t + 1];
  tok_sorted[p0] = t; route_pos[2 * t]     = p0;
  tok_sorted[p1] = t; route_pos[2 * t + 1] = p1;
}

// ------- grouped expert GEMM: TM=64, TN=128, BK=32, dbuf async LDS, tile-list grid ----
// blockIdx.x indexes the flat tile list (every block does real work; no skew).
template<bool OUT_F32, bool RELU>
__global__ __launch_bounds__(256) void moe_gemm_kernel(const __bf16* __restrict__ A,
                                                       const __bf16* __restrict__ Bt,
                                                       const float* __restrict__ bias,
                                                       void* __restrict__ out,
                                                       const int* __restrict__ seg_off,
                                                       const int* __restrict__ gather,
                                                       const int* __restrict__ tile_e,
                                                       const int* __restrict__ tile_mt,
                                                       const int* __restrict__ ntiles,
                                                       int K, int N) {
  int bx = blockIdx.x;
  if (bx >= *ntiles) return;
  int e  = tile_e[bx];
  int mt = tile_mt[bx];
  int off = seg_off[e];
  int Te  = seg_off[e + 1] - off;
  int nt = blockIdx.y;

  __shared__ __bf16 Al[2][64][32];
  __shared__ __bf16 Bl[2][128][32];

  int tid = threadIdx.x;
  int lane = tid & 63, w = tid >> 6;
  int l16 = lane & 15, quad = lane >> 4;

  int r0 = tid >> 2, q8 = (tid & 3) * 8;
  int rowA = mt * 64 + r0;
  int rA = rowA < Te ? rowA : Te - 1;
  size_t ga = gather ? (size_t)gather[off + rA] : (size_t)(off + rA);
  const __bf16* apg  = A + ga * K + q8;
  const __bf16* Bte  = Bt + (size_t)e * N * K;
  const __bf16* bpg0 = Bte + (size_t)(nt * 128 + r0) * K + q8;
  const __bf16* bpg1 = bpg0 + (size_t)64 * K;

  __bf16* al0 = &Al[0][0][0];
  __bf16* al1 = &Al[1][0][0];
  __bf16* bl0 = &Bl[0][0][0];
  __bf16* bl1 = &Bl[1][0][0];

  f32x4 acc[4][2];
  #pragma unroll
  for (int i = 0; i < 4; i++)
    #pragma unroll
    for (int j = 0; j < 2; j++) acc[i][j] = {0.f, 0.f, 0.f, 0.f};

  async_cp16(apg, al0 + tid * 8);
  async_cp16(bpg0, bl0 + tid * 8);
  async_cp16(bpg1, bl0 + (tid + 256) * 8);

  int nIter = K >> 5;
  for (int it = 0; it < nIter; ++it) {
    int buf = it & 1;
    if (it + 1 < nIter) {
      int kb = (it + 1) << 5;
      __bf16* an = buf ? al0 : al1;
      __bf16* bn = buf ? bl0 : bl1;
      async_cp16(apg + kb, an + tid * 8);
      async_cp16(bpg0 + kb, bn + tid * 8);
      async_cp16(bpg1 + kb, bn + (tid + 256) * 8);
      asm volatile("s_waitcnt vmcnt(3)" ::: "memory");
    } else {
      asm volatile("s_waitcnt vmcnt(0)" ::: "memory");
    }
    __builtin_amdgcn_s_barrier();
    asm volatile("" ::: "memory");
    const __bf16* ab = buf ? al1 : al0;
    const __bf16* bb = buf ? bl1 : bl0;
    bf16x8 af[4], bfr[2];
    #pragma unroll
    for (int i = 0; i < 4; i++)
      af[i] = *(const bf16x8*)(ab + (size_t)(i * 16 + l16) * 32 + quad * 8);
    #pragma unroll
    for (int i = 0; i < 2; i++)
      bfr[i] = *(const bf16x8*)(bb + (size_t)(w * 32 + i * 16 + l16) * 32 + quad * 8);
    #pragma unroll
    for (int mi = 0; mi < 4; mi++)
      #pragma unroll
      for (int ni = 0; ni < 2; ni++)
        acc[mi][ni] = __builtin_amdgcn_mfma_f32_16x16x32_bf16(af[mi], bfr[ni], acc[mi][ni], 0, 0, 0);
    asm volatile("" ::: "memory");
    __builtin_amdgcn_s_barrier();
  }

  const float* be = bias + (size_t)e * N;
  #pragma unroll
  for (int ni = 0; ni < 2; ni++) {
    int col = nt * 128 + w * 32 + ni * 16 + l16;
    float bv = be[col];
    #pragma unroll
    for (int mi = 0; mi < 4; mi++) {
      #pragma unroll
      for (int r = 0; r < 4; r++) {
        int row_in = mt * 64 + mi * 16 + quad * 4 + r;
        if (row_in < Te) {
          float v = acc[mi][ni][r] + bv;
          if (RELU) v = fmaxf(v, 0.f);
          size_t orow = (size_t)(off + row_in);
          if (OUT_F32) ((float*)out)[orow * N + col] = v;
          else ((__bf16*)out)[orow * N + col] = (__bf16)v;
        }
      }
    }
  }
}

// ---------------- final combine: out[t] = g0*Y[p0] + g1*Y[p1] ----------------
__global__ void combine_kernel(const float* __restrict__ Y, const int* __restrict__ route_pos,
                               const float2* __restrict__ g01, float* __restrict__ out) {
  int gid = blockIdx.x * blockDim.x + threadIdx.x;
  int t = gid >> 6, c = (gid & 63) << 2;
  if (t >= NTOK) return;
  int p0 = route_pos[2 * t], p1 = route_pos[2 * t + 1];
  float2 g = g01[t];
  float4 y0 = *(const float4*)&Y[(size_t)p0 * DOUT + c];
  float4 y1 = *(const float4*)&Y[(size_t)p1 * DOUT + c];
  float4 o;
  o.x = g.x * y0.x + g.y * y1.x;
  o.y = g.x * y0.y + g.y * y1.y;
  o.z = g.x * y0.z + g.y * y1.z;
  o.w = g.x * y0.w + g.y * y1.w;
  *(float4*)&out[(size_t)t * DOUT + c] = o;
}

// ---------------- launcher ----------------
extern "C" void kernel_launch(void* const* d_in, const int* in_sizes, int n_in,
                              void* d_out, int out_size, void* d_ws, size_t ws_size,
                              hipStream_t stream) {
  const float* x          = (const float*)d_in[0];
  const float* gate_w     = (const float*)d_in[1];
  const float* gate_b     = (const float*)d_in[2];
  const float* gate_out_w = (const float*)d_in[3];
  const float* gate_out_b = (const float*)d_in[4];
  const float* w1         = (const float*)d_in[5];
  const float* b1         = (const float*)d_in[6];
  const float* w2         = (const float*)d_in[7];
  const float* b2         = (const float*)d_in[8];
  const float* w3         = (const float*)d_in[9];
  const float* b3         = (const float*)d_in[10];
  float* out = (float*)d_out;

  char* ws = (char*)d_ws;
  size_t o = 0;
  auto alloc = [&](size_t bytes) -> void* {
    o = (o + 255) & ~(size_t)255;
    void* p = ws + o;
    o += bytes;
    return p;
  };

  __bf16* xb   = (__bf16*)alloc((size_t)NTOK * DIN * 2);
  __bf16* w1t  = (__bf16*)alloc((size_t)NEXP * HID * DIN * 2);
  __bf16* w2t  = (__bf16*)alloc((size_t)NEXP * HID * HID * 2);
  __bf16* w3t  = (__bf16*)alloc((size_t)NEXP * DOUT * HID * 2);
  size_t r1 = (size_t)NTOK * HID * 4;
  size_t r2 = (size_t)(NKA + 128) * HID * 2;
  void* region1 = alloc(r1 > r2 ? r1 : r2);   // hg (fp32) aliases H1 (bf16); hg dead first
  float*  hg = (float*)region1;
  __bf16* H1 = (__bf16*)region1;
  float* logits    = (float*)alloc((size_t)NTOK * 16 * 4);
  int2*  e01       = (int2*)alloc((size_t)NTOK * 8);
  float2* g01      = (float2*)alloc((size_t)NTOK * 8);
  int*   offsets   = (int*)alloc((NEXP + 1) * 4);
  int*   blockhist = (int*)alloc((size_t)NBLK * NEXP * 4);
  int*   base      = (int*)alloc((size_t)NBLK * NEXP * 4);
  int*   lrank     = (int*)alloc((size_t)NTOK * 2 * 4);
  int*   tok_sorted= (int*)alloc((size_t)(NKA + 128) * 4);
  int*   route_pos = (int*)alloc((size_t)NTOK * 2 * 4);
  int*   tile_e    = (int*)alloc(MAXTILE * 4);
  int*   tile_mt   = (int*)alloc(MAXTILE * 4);
  int*   ntiles    = (int*)alloc(4);
  __bf16* H2       = (__bf16*)alloc((size_t)(NKA + 128) * HID * 2);
  float*  Y        = (float*)alloc((size_t)(NKA + 128) * DOUT * 4);
  (void)ws_size; (void)n_in; (void)in_sizes; (void)out_size;

  cvt_x_kernel<<<(NTOK * DIN / 4) / 256, 256, 0, stream>>>(x, xb);

  dim3 tb(32, 8);
  transpose_cvt_kernel<<<dim3(DIN / 32, HID / 32, NEXP), tb, 0, stream>>>(w1, w1t, DIN, HID);
  transpose_cvt_kernel<<<dim3(HID / 32, HID / 32, NEXP), tb, 0, stream>>>(w2, w2t, HID, HID);
  transpose_cvt_kernel<<<dim3(HID / 32, DOUT / 32, NEXP), tb, 0, stream>>>(w3, w3t, HID, DOUT);

  gate_gemm_kernel<<<dim3(NTOK / 128, HID / 128), 256, 0, stream>>>(x, gate_w, gate_b, hg);
  logits_kernel<<<NTOK / 8, 128, 0, stream>>>(hg, gate_out_w, gate_out_b, logits);
  top2_route_kernel<<<NBLK, 256, 0, stream>>>(logits, e01, g01, lrank, blockhist);
  scan2_kernel<<<1, 64, 0, stream>>>(blockhist, offsets, base, tile_e, tile_mt, ntiles);
  fill2_kernel<<<NBLK, 256, 0, stream>>>(e01, lrank, base, tok_sorted, route_pos);

  moe_gemm_kernel<false, true><<<dim3(MAXTILE, HID / 128), 256, 0, stream>>>(
      xb, w1t, b1, H1, offsets, tok_sorted, tile_e, tile_mt, ntiles, DIN, HID);
  moe_gemm_kernel<false, true><<<dim3(MAXTILE, HID / 128), 256, 0, stream>>>(
      H1, w2t, b2, H2, offsets, nullptr, tile_e, tile_mt, ntiles, HID, HID);
  moe_gemm_kernel<true, false><<<dim3(MAXTILE, DOUT / 128), 256, 0, stream>>>(
      H2, w3t, b3, Y, offsets, nullptr, tile_e, tile_mt, ntiles, HID, DOUT);

  combine_kernel<<<(NTOK * 64) / 256, 256, 0, stream>>>(Y, route_pos, g01, out);
}